// Round 3
// baseline (325.495 us; speedup 1.0000x reference)
//
#include <hip/hip_runtime.h>
#include <hip/hip_cooperative_groups.h>

namespace cg = cooperative_groups;

// Problem constants (from reference)
#define N_CAM   6
#define N_HEADS 8
#define EMBD    256
#define HS      32
#define L       100     // seq_len = 10*10
#define BS      2
#define CAM_STRIDE (L * EMBD)   // 25600 floats per (b, cam)
#define CK      (N_CAM * L)     // 600 combined (cam, sk) index

// Workspace layout (floats):
//   wsum : 1536*256 = 393216   folded W (sum over 4 ref slots)  [L2-resident]
//   ktr  : 2*8*8*600 float4 = 307200 floats  [b][h][d4][ck] float4-packed K
//   P    : 200*256*4 = 204800  split-K partials, float4 per (row,e): .c = chunk
//   E    : 200*8*100 = 160000  E[b*100+sq][h][sk] (camera-folded exp scores)
#define WS_WSUM 0
#define WS_KTR  (WS_WSUM + 1536 * 256)
#define WS_P    (WS_KTR + 2 * N_HEADS * 8 * CK * 4)
#define WS_E    (WS_P + 200 * 256 * 4)

// Stage job counts
#define S1_JOBS 480   // 96 transpose + 384 W-fold
#define S2_JOBS 600   // 200 GEMM (4-row) + 400 E
#define S3_JOBS 100   // 2 sq per job
#define GRID    512   // 2 blocks/CU co-resident (13.6KB LDS, 56 VGPR)

// ---------------------------------------------------------------------------
// Fused cooperative kernel, STATIC scheduling (R2 post-mortem: the global
// atomic work-stealing counter cost ~130us — 850 contended cross-XCD RMWs.
// Static round-robin has zero arbitration cost; 512 blocks give 8 waves/CU
// for latency hiding and cap stage-2 at <=2 jobs/block, interleaved GEMM+E).
// ---------------------------------------------------------------------------
__global__ __launch_bounds__(256) void fused_kernel(const float* __restrict__ feat,
                                                    const float* __restrict__ query,
                                                    const float4* __restrict__ Wv4,
                                                    const float* __restrict__ b_v,
                                                    float* __restrict__ out,
                                                    float* __restrict__ ws) {
    cg::grid_group grid = cg::this_grid();
    __shared__ float smem[3400];   // union: tile 3300 | a_tile 1536 | q_s+es 2528 | E_s 1600
    const int t = threadIdx.x;

    // ======================= Stage 1: prep (480 jobs, static) ==============
    for (int job = blockIdx.x; job < S1_JOBS; job += GRID) {
        __syncthreads();               // protect smem reuse across jobs
        if (job < 96) {
            float* tile = smem;        // 100*33 = 3300 floats, +1-pad columns
            int b   = job / 48;
            int rem = job - b * 48;
            int cam = rem >> 3;
            int h   = rem & 7;
            const float4* src4 = reinterpret_cast<const float4*>(
                feat + (size_t)(b * N_CAM + cam) * CAM_STRIDE + h * HS);
            for (int idx = t; idx < 100 * 8; idx += 256) {
                int sk = idx >> 3;
                int d4 = idx & 7;
                float4 v = src4[sk * (EMBD / 4) + d4];    // 128B-contiguous runs
                float* dst = &tile[sk * 33 + d4 * 4];
                dst[0] = v.x; dst[1] = v.y; dst[2] = v.z; dst[3] = v.w;
            }
            __syncthreads();
            float4* ktr4 = reinterpret_cast<float4*>(ws + WS_KTR)
                         + (size_t)(b * N_HEADS + h) * 8 * CK + cam * L;
            for (int idx = t; idx < 8 * 100; idx += 256) {
                int d4 = idx / 100;
                int sk = idx - d4 * 100;
                const float* s = &tile[sk * 33 + d4 * 4]; // banks cycle (33%32==1)
                ktr4[(size_t)d4 * CK + sk] = make_float4(s[0], s[1], s[2], s[3]);
            }
        } else {
            // wsum[i][e] = sum_ref W_v[i][ref*256+e]
            int tid = (job - 96) * 256 + t;
            int i  = tid >> 6;
            int e4 = tid & 63;
            const float4* row = Wv4 + (size_t)i * 256;
            float4 a = row[e4];
            float4 b = row[64 + e4];
            float4 c = row[128 + e4];
            float4 d = row[192 + e4];
            float4 o;
            o.x = a.x + b.x + c.x + d.x;
            o.y = a.y + b.y + c.y + d.y;
            o.z = a.z + b.z + c.z + d.z;
            o.w = a.w + b.w + c.w + d.w;
            ((float4*)(ws + WS_WSUM))[(size_t)i * 64 + e4] = o;
        }
    }

    __threadfence();
    grid.sync();

    // ======== Stage 2: GEMM partials (200 jobs) + E-compute (400 jobs) =====
    // Static round-robin: block b takes jobs {b, b+512} -> max 1 GEMM + 1 E.
    for (int job = blockIdx.x; job < S2_JOBS; job += GRID) {
        __syncthreads();               // previous job's smem reads complete
        if (job < 200) {
            // ---- GEMM: 4 rows x 384-K-chunk; P packed float4/(row,e) ----
            float* a_tile = smem;      // 1536 floats
            const int rg = job >> 2;   // 0..49
            const int c  = job & 3;    // K-chunk
            const int r0 = rg * 4;
            const int k0 = c * 384;

            for (int i = t; i < 4 * 384; i += 256) {
                int j  = i / 384;
                int kk = i - j * 384;
                int k  = k0 + kk;
                int cam = k >> 8, e2 = k & 255;
                int row = r0 + j;
                int b = row >= 100;
                int s = row - b * 100;
                a_tile[i] = feat[(size_t)(b * N_CAM + cam) * CAM_STRIDE + s * EMBD + e2];
            }
            __syncthreads();

            float acc0 = 0.f, acc1 = 0.f, acc2 = 0.f, acc3 = 0.f;
            const float* wp = ws + WS_WSUM + (size_t)k0 * 256 + t;
#pragma unroll 32
            for (int kk = 0; kk < 384; ++kk) {
                float w = wp[(size_t)kk * 256];   // coalesced, L2/L3-hit
                acc0 += a_tile[kk] * w;           // LDS broadcast (free)
                acc1 += a_tile[384 + kk] * w;
                acc2 += a_tile[768 + kk] * w;
                acc3 += a_tile[1152 + kk] * w;
            }

            float* P = ws + WS_P;
            P[((size_t)(r0 + 0) * 256 + t) * 4 + c] = acc0;
            P[((size_t)(r0 + 1) * 256 + t) * 4 + c] = acc1;
            P[((size_t)(r0 + 2) * 256 + t) * 4 + c] = acc2;
            P[((size_t)(r0 + 3) * 256 + t) * 4 + c] = acc3;
        } else {
            // ---- E branch: job = (b, h, sq-tile of 4) ----
            float* q_s = smem;         // 128 floats
            float* es  = smem + 128;   // 2400 floats
            int idx = job - 200;       // [0,400)
            int b   = idx / 200;
            int rem = idx - b * 200;
            int h   = rem / 25;
            int sqt = rem - h * 25;
            int sq0 = sqt * 4;

            if (t < 128)
                q_s[t] = query[(size_t)(b * L + sq0 + (t >> 5)) * EMBD + h * HS + (t & 31)];
            __syncthreads();

            const float scale = 0.17677669529663687f;  // 1/sqrt(32)
            const float4* kt4 = reinterpret_cast<const float4*>(ws + WS_KTR)
                              + (size_t)(b * N_HEADS + h) * 8 * CK;

#pragma unroll
            for (int i = 0; i < 3; ++i) {
                int ck = t + i * 256;
                if (ck < CK) {
                    float acc0 = 0.f, acc1 = 0.f, acc2 = 0.f, acc3 = 0.f;
#pragma unroll
                    for (int d4 = 0; d4 < 8; ++d4) {
                        float4 kv = kt4[(size_t)d4 * CK + ck];   // 16B/lane coalesced
                        const float* q0 = &q_s[0 * 32 + d4 * 4];
                        const float* q1 = &q_s[1 * 32 + d4 * 4];
                        const float* q2 = &q_s[2 * 32 + d4 * 4];
                        const float* q3 = &q_s[3 * 32 + d4 * 4];
                        acc0 += q0[0] * kv.x + q0[1] * kv.y + q0[2] * kv.z + q0[3] * kv.w;
                        acc1 += q1[0] * kv.x + q1[1] * kv.y + q1[2] * kv.z + q1[3] * kv.w;
                        acc2 += q2[0] * kv.x + q2[1] * kv.y + q2[2] * kv.z + q2[3] * kv.w;
                        acc3 += q3[0] * kv.x + q3[1] * kv.y + q3[2] * kv.z + q3[3] * kv.w;
                    }
                    es[0 * CK + ck] = __expf(acc0 * scale);
                    es[1 * CK + ck] = __expf(acc1 * scale);
                    es[2 * CK + ck] = __expf(acc2 * scale);
                    es[3 * CK + ck] = __expf(acc3 * scale);
                }
            }
            __syncthreads();

            // camera fold -> E
            float* E = ws + WS_E;
            for (int p = t; p < 4 * L; p += 256) {
                int sj = p / 100, sk = p - sj * 100;
                float e = 0.f;
#pragma unroll
                for (int cam = 0; cam < N_CAM; ++cam)
                    e += es[sj * CK + cam * L + sk];
                E[((size_t)(b * L + sq0 + sj) * N_HEADS + h) * L + sk] = e;
            }
        }
    }

    __threadfence();
    grid.sync();

    // ================= Stage 3: output (100 jobs, 2 sq each, static) =======
    for (int job = blockIdx.x; job < S3_JOBS; job += GRID) {
        __syncthreads();
        float* E_s = smem;             // 1600 floats
        const int b   = job / 50;
        const int sq0 = (job - b * 50) * 2;

        const float* E = ws + WS_E + (size_t)(b * L + sq0) * N_HEADS * L;
        for (int i = t; i < 2 * N_HEADS * L; i += 256) E_s[i] = E[i];
        __syncthreads();

        const int h = t >> 5;
        float sumE0 = 0.f, sumE1 = 0.f;
#pragma unroll 4
        for (int sk = 0; sk < L; ++sk) {
            sumE0 += E_s[h * L + sk];                 // broadcast reads (free)
            sumE1 += E_s[N_HEADS * L + h * L + sk];
        }

        float bias = b_v[t] + b_v[256 + t] + b_v[512 + t] + b_v[768 + t];

        const float4* p4 = (const float4*)(ws + WS_P) + (size_t)b * L * 256 + t;
        float acc0 = 0.f, acc1 = 0.f;
#pragma unroll 16
        for (int sk = 0; sk < L; ++sk) {
            float4 p = p4[(size_t)sk * 256];  // 16B coalesced, folds 4 K-chunks
            float s = p.x + p.y + p.z + p.w;
            acc0 += E_s[h * L + sk] * s;
            acc1 += E_s[N_HEADS * L + h * L + sk] * s;
        }

        out[(size_t)(b * L + sq0 + 0) * EMBD + t] = (acc0 + sumE0 * bias) * (0.25f / sumE0);
        out[(size_t)(b * L + sq0 + 1) * EMBD + t] = (acc1 + sumE1 * bias) * (0.25f / sumE1);
    }
}

// ---------------------------------------------------------------------------
// Fallback (non-cooperative) 3-kernel pipeline — identical math, used only if
// cooperative launch fails (e.g. co-residency not granted).
// ---------------------------------------------------------------------------
__global__ __launch_bounds__(256) void prep_kernel(const float* __restrict__ feat,
                                                   const float4* __restrict__ Wv4,
                                                   float* __restrict__ ws) {
    const int t = threadIdx.x;
    if (blockIdx.x < 96) {
        __shared__ float tile[100 * 33];
        int blk = blockIdx.x;
        int b   = blk / 48;
        int rem = blk - b * 48;
        int cam = rem >> 3;
        int h   = rem & 7;
        const float4* src4 = reinterpret_cast<const float4*>(
            feat + (size_t)(b * N_CAM + cam) * CAM_STRIDE + h * HS);
        for (int idx = t; idx < 100 * 8; idx += 256) {
            int sk = idx >> 3;
            int d4 = idx & 7;
            float4 v = src4[sk * (EMBD / 4) + d4];
            float* dst = &tile[sk * 33 + d4 * 4];
            dst[0] = v.x; dst[1] = v.y; dst[2] = v.z; dst[3] = v.w;
        }
        __syncthreads();
        float4* ktr4 = reinterpret_cast<float4*>(ws + WS_KTR)
                     + (size_t)(b * N_HEADS + h) * 8 * CK + cam * L;
        for (int idx = t; idx < 8 * 100; idx += 256) {
            int d4 = idx / 100;
            int sk = idx - d4 * 100;
            const float* s = &tile[sk * 33 + d4 * 4];
            ktr4[(size_t)d4 * CK + sk] = make_float4(s[0], s[1], s[2], s[3]);
        }
    } else {
        int tid = (blockIdx.x - 96) * 256 + t;
        int i  = tid >> 6;
        int e4 = tid & 63;
        const float4* row = Wv4 + (size_t)i * 256;
        float4 a = row[e4];
        float4 b = row[64 + e4];
        float4 c = row[128 + e4];
        float4 d = row[192 + e4];
        float4 o;
        o.x = a.x + b.x + c.x + d.x;
        o.y = a.y + b.y + c.y + d.y;
        o.z = a.z + b.z + c.z + d.z;
        o.w = a.w + b.w + c.w + d.w;
        ((float4*)(ws + WS_WSUM))[(size_t)i * 64 + e4] = o;
    }
}

__global__ __launch_bounds__(256) void mid_kernel(const float* __restrict__ feat,
                                                  const float* __restrict__ query,
                                                  const float* __restrict__ ws_r,
                                                  float* __restrict__ ws_w) {
    const int t = threadIdx.x;
    if (blockIdx.x < 200) {
        __shared__ float a_tile[4 * 384];
        const int rg = blockIdx.x >> 2;
        const int c  = blockIdx.x & 3;
        const int r0 = rg * 4;
        const int k0 = c * 384;

        for (int i = t; i < 4 * 384; i += 256) {
            int j  = i / 384;
            int kk = i - j * 384;
            int k  = k0 + kk;
            int cam = k >> 8, e2 = k & 255;
            int row = r0 + j;
            int b = row >= 100;
            int s = row - b * 100;
            a_tile[i] = feat[(size_t)(b * N_CAM + cam) * CAM_STRIDE + s * EMBD + e2];
        }
        __syncthreads();

        float acc0 = 0.f, acc1 = 0.f, acc2 = 0.f, acc3 = 0.f;
        const float* wp = ws_r + WS_WSUM + (size_t)k0 * 256 + t;
#pragma unroll 32
        for (int kk = 0; kk < 384; ++kk) {
            float w = wp[(size_t)kk * 256];
            acc0 += a_tile[kk] * w;
            acc1 += a_tile[384 + kk] * w;
            acc2 += a_tile[768 + kk] * w;
            acc3 += a_tile[1152 + kk] * w;
        }

        float* P = ws_w + WS_P;
        P[((size_t)(r0 + 0) * 256 + t) * 4 + c] = acc0;
        P[((size_t)(r0 + 1) * 256 + t) * 4 + c] = acc1;
        P[((size_t)(r0 + 2) * 256 + t) * 4 + c] = acc2;
        P[((size_t)(r0 + 3) * 256 + t) * 4 + c] = acc3;
    } else {
        __shared__ float q_s[4 * 32];
        __shared__ float es[4 * CK];
        int idx = blockIdx.x - 200;
        int b   = idx / 200;
        int rem = idx - b * 200;
        int h   = rem / 25;
        int sqt = rem - h * 25;
        int sq0 = sqt * 4;

        if (t < 128)
            q_s[t] = query[(size_t)(b * L + sq0 + (t >> 5)) * EMBD + h * HS + (t & 31)];
        __syncthreads();

        const float scale = 0.17677669529663687f;
        const float4* kt4 = reinterpret_cast<const float4*>(ws_r + WS_KTR)
                          + (size_t)(b * N_HEADS + h) * 8 * CK;

#pragma unroll
        for (int i = 0; i < 3; ++i) {
            int ck = t + i * 256;
            if (ck < CK) {
                float acc0 = 0.f, acc1 = 0.f, acc2 = 0.f, acc3 = 0.f;
#pragma unroll
                for (int d4 = 0; d4 < 8; ++d4) {
                    float4 kv = kt4[(size_t)d4 * CK + ck];
                    const float* q0 = &q_s[0 * 32 + d4 * 4];
                    const float* q1 = &q_s[1 * 32 + d4 * 4];
                    const float* q2 = &q_s[2 * 32 + d4 * 4];
                    const float* q3 = &q_s[3 * 32 + d4 * 4];
                    acc0 += q0[0] * kv.x + q0[1] * kv.y + q0[2] * kv.z + q0[3] * kv.w;
                    acc1 += q1[0] * kv.x + q1[1] * kv.y + q1[2] * kv.z + q1[3] * kv.w;
                    acc2 += q2[0] * kv.x + q2[1] * kv.y + q2[2] * kv.z + q2[3] * kv.w;
                    acc3 += q3[0] * kv.x + q3[1] * kv.y + q3[2] * kv.z + q3[3] * kv.w;
                }
                es[0 * CK + ck] = __expf(acc0 * scale);
                es[1 * CK + ck] = __expf(acc1 * scale);
                es[2 * CK + ck] = __expf(acc2 * scale);
                es[3 * CK + ck] = __expf(acc3 * scale);
            }
        }
        __syncthreads();

        float* E = ws_w + WS_E;
        for (int p = t; p < 4 * L; p += 256) {
            int sj = p / 100, sk = p - sj * 100;
            float e = 0.f;
#pragma unroll
            for (int cam = 0; cam < N_CAM; ++cam)
                e += es[sj * CK + cam * L + sk];
            E[((size_t)(b * L + sq0 + sj) * N_HEADS + h) * L + sk] = e;
        }
    }
}

__global__ __launch_bounds__(256) void out_kernel(const float* __restrict__ ws,
                                                  const float* __restrict__ b_v,
                                                  float* __restrict__ out) {
    __shared__ float E_s[2 * N_HEADS * L];
    const int t   = threadIdx.x;
    const int b   = blockIdx.x / 50;
    const int sq0 = (blockIdx.x - b * 50) * 2;

    const float* E = ws + WS_E + (size_t)(b * L + sq0) * N_HEADS * L;
    for (int i = t; i < 2 * N_HEADS * L; i += 256) E_s[i] = E[i];
    __syncthreads();

    const int h = t >> 5;
    float sumE0 = 0.f, sumE1 = 0.f;
#pragma unroll 4
    for (int sk = 0; sk < L; ++sk) {
        sumE0 += E_s[h * L + sk];
        sumE1 += E_s[N_HEADS * L + h * L + sk];
    }

    float bias = b_v[t] + b_v[256 + t] + b_v[512 + t] + b_v[768 + t];

    const float4* p4 = (const float4*)(ws + WS_P) + (size_t)b * L * 256 + t;
    float acc0 = 0.f, acc1 = 0.f;
#pragma unroll 16
    for (int sk = 0; sk < L; ++sk) {
        float4 p = p4[(size_t)sk * 256];
        float s = p.x + p.y + p.z + p.w;
        acc0 += E_s[h * L + sk] * s;
        acc1 += E_s[N_HEADS * L + h * L + sk] * s;
    }

    out[(size_t)(b * L + sq0 + 0) * EMBD + t] = (acc0 + sumE0 * bias) * (0.25f / sumE0);
    out[(size_t)(b * L + sq0 + 1) * EMBD + t] = (acc1 + sumE1 * bias) * (0.25f / sumE1);
}

// ---------------------------------------------------------------------------
extern "C" void kernel_launch(void* const* d_in, const int* in_sizes, int n_in,
                              void* d_out, int out_size, void* d_ws, size_t ws_size,
                              hipStream_t stream) {
    const float* feat  = (const float*)d_in[0];  // (2,1,6,256,10,10)
    const float* query = (const float*)d_in[1];  // (2,100,256)
    const float4* Wv   = (const float4*)d_in[2]; // (1536,1024)
    const float* bv    = (const float*)d_in[3];  // (1024,)
    float* outp = (float*)d_out;                 // (2,100,256)
    float* ws   = (float*)d_ws;

    void* args[] = {(void*)&feat, (void*)&query, (void*)&Wv, (void*)&bv,
                    (void*)&outp, (void*)&ws};
    hipError_t err = hipLaunchCooperativeKernel((const void*)fused_kernel,
                                                dim3(GRID), dim3(256),
                                                args, 0, stream);
    if (err != hipSuccess) {
        // Fallback: classic 3-launch pipeline (identical math)
        prep_kernel<<<480, 256, 0, stream>>>(feat, Wv, ws);
        mid_kernel<<<600, 256, 0, stream>>>(feat, query, ws, ws);
        out_kernel<<<100, 256, 0, stream>>>(ws, bv, outp);
    }
}

// Round 4
// 94.378 us; speedup vs baseline: 3.4488x; 3.4488x over previous
//
#include <hip/hip_runtime.h>

// Problem constants (from reference)
#define N_CAM   6
#define N_HEADS 8
#define EMBD    256
#define HS      32
#define L       100     // seq_len = 10*10
#define BS      2
#define CAM_STRIDE (L * EMBD)   // 25600 floats per (b, cam)
#define CK      (N_CAM * L)     // 600 combined (cam, sk) index

// Workspace layout (floats):
//   wsum : 1536*256 = 393216   folded W (sum over 4 ref slots)  [L2-resident]
//   ktr  : 2*8*8*600 float4 = 307200 floats  [b][h][d4][ck] float4-packed K
//   P    : 200*256*4 = 204800  split-K partials, float4 per (row,e): .c = chunk
//   E    : 200*8*100 = 160000  E[b*100+sq][h][sk] (camera-folded exp scores)
#define WS_WSUM 0
#define WS_KTR  (WS_WSUM + 1536 * 256)
#define WS_P    (WS_KTR + 2 * N_HEADS * 8 * CK * 4)
#define WS_E    (WS_P + 200 * 256 * 4)

// R3 post-mortem: cooperative grid.sync costs ~0.23us/block/sync on MI355X
// (R2: 256blk+2sync=156us; R3: 512blk+2sync=257us; real work ~10us).
// Cooperative fusion is structurally unviable -> 3 stream-ordered launches
// (gaps ~2-4us each). All optimization goes into the kernels themselves.

// ---------------------------------------------------------------------------
// L1 (480 blocks) — independent prep jobs (measured-good, unchanged):
//  blocks [0,96):  transpose feat -> ktr4[b][h][d4][cam*100+sk] (float4 over d)
//  blocks [96,480): fold W_v (1536x1024) over 4 ref slots -> wsum (1536x256)
// ---------------------------------------------------------------------------
__global__ __launch_bounds__(256) void prep_kernel(const float* __restrict__ feat,
                                                   const float4* __restrict__ Wv4,
                                                   float* __restrict__ ws) {
    const int t = threadIdx.x;
    if (blockIdx.x < 96) {
        __shared__ float tile[100 * 33];  // +1 pad: conflict-free column reads
        int blk = blockIdx.x;
        int b   = blk / 48;
        int rem = blk - b * 48;
        int cam = rem >> 3;
        int h   = rem & 7;
        const float4* src4 = reinterpret_cast<const float4*>(
            feat + (size_t)(b * N_CAM + cam) * CAM_STRIDE + h * HS);
        for (int idx = t; idx < 100 * 8; idx += 256) {
            int sk = idx >> 3;
            int d4 = idx & 7;
            float4 v = src4[sk * (EMBD / 4) + d4];       // 128B-contiguous runs
            float* dst = &tile[sk * 33 + d4 * 4];
            dst[0] = v.x; dst[1] = v.y; dst[2] = v.z; dst[3] = v.w;
        }
        __syncthreads();
        float4* ktr4 = reinterpret_cast<float4*>(ws + WS_KTR)
                     + (size_t)(b * N_HEADS + h) * 8 * CK + cam * L;
        for (int idx = t; idx < 8 * 100; idx += 256) {
            int d4 = idx / 100;
            int sk = idx - d4 * 100;
            const float* s = &tile[sk * 33 + d4 * 4];    // banks cycle (33%32==1)
            ktr4[(size_t)d4 * CK + sk] = make_float4(s[0], s[1], s[2], s[3]);
        }
    } else {
        // wsum[i][e] = sum_ref W_v[i][ref*256+e]
        int tid = (blockIdx.x - 96) * 256 + t;
        int i  = tid >> 6;
        int e4 = tid & 63;
        const float4* row = Wv4 + (size_t)i * 256;
        float4 a = row[e4];
        float4 b = row[64 + e4];
        float4 c = row[128 + e4];
        float4 d = row[192 + e4];
        float4 o;
        o.x = a.x + b.x + c.x + d.x;
        o.y = a.y + b.y + c.y + d.y;
        o.z = a.z + b.z + c.z + d.z;
        o.w = a.w + b.w + c.w + d.w;
        ((float4*)(ws + WS_WSUM))[(size_t)i * 64 + e4] = o;
    }
}

// ---------------------------------------------------------------------------
// L2 (600 blocks) — GEMM partials + E-compute, co-scheduled for TLP:
//  blocks [0,200):  split-K GEMM, 4 rows/block, FLOAT4 wsum loads.
//    Wave g (=tid>>6) owns kk-phase g: per iter one coalesced 1KB float4 wsum
//    read + 16 FMA (96 iters vs 384 scalar). Cross-wave LDS reduction at end.
//    wsum L2 traffic 78.6 MB; P layout byte-identical float4/(row,e), .c=chunk.
//  blocks [200,600): E from float4-packed ktr (measured-good, unchanged).
// ---------------------------------------------------------------------------
__global__ __launch_bounds__(256) void mid_kernel(const float* __restrict__ feat,
                                                  const float* __restrict__ query,
                                                  const float* __restrict__ ws_r,
                                                  float* __restrict__ ws_w) {
    const int t = threadIdx.x;
    if (blockIdx.x < 200) {
        // ---- GEMM: 4 rows x 384-K-chunk per block ----
        __shared__ float  a_tile[4 * 384];       // 6 KB
        __shared__ float4 red4[4 * 4 * 64];      // [g][row][e4], 16 KB
        const int rg = blockIdx.x >> 2;          // 0..49
        const int c  = blockIdx.x & 3;           // K-chunk
        const int r0 = rg * 4;                   // 0..196 (no b-straddle)
        const int k0 = c * 384;

        for (int i = t; i < 4 * 384; i += 256) {
            int j  = i / 384;
            int kk = i - j * 384;
            int k  = k0 + kk;
            int cam = k >> 8, e2 = k & 255;
            int row = r0 + j;
            int b = row >= 100;
            int s = row - b * 100;
            a_tile[i] = feat[(size_t)(b * N_CAM + cam) * CAM_STRIDE + s * EMBD + e2];
        }
        __syncthreads();

        const int g  = t >> 6;      // wave id = kk phase (0..3)
        const int e4 = t & 63;      // owns e = 4*e4 .. 4*e4+3
        float4 acc0 = {0.f,0.f,0.f,0.f}, acc1 = acc0, acc2 = acc0, acc3 = acc0;
        // wsum4[(k0+kk)*64 + e4], kk = 4*kk2 + g  ->  base + kk2*256
        const float4* wp4 = (const float4*)(ws_r + WS_WSUM)
                          + (size_t)(k0 + g) * 64 + e4;
#pragma unroll 16
        for (int kk2 = 0; kk2 < 96; ++kk2) {
            float4 w = wp4[(size_t)kk2 * 256];   // 1KB/wave coalesced, L2-hit
            int kk = kk2 * 4 + g;
            float a0 = a_tile[kk];               // wave-uniform LDS broadcast
            float a1 = a_tile[384 + kk];
            float a2 = a_tile[768 + kk];
            float a3 = a_tile[1152 + kk];
            acc0.x += a0 * w.x; acc0.y += a0 * w.y; acc0.z += a0 * w.z; acc0.w += a0 * w.w;
            acc1.x += a1 * w.x; acc1.y += a1 * w.y; acc1.z += a1 * w.z; acc1.w += a1 * w.w;
            acc2.x += a2 * w.x; acc2.y += a2 * w.y; acc2.z += a2 * w.z; acc2.w += a2 * w.w;
            acc3.x += a3 * w.x; acc3.y += a3 * w.y; acc3.z += a3 * w.z; acc3.w += a3 * w.w;
        }

        // cross-wave (kk-phase) reduction via LDS
        red4[(g * 4 + 0) * 64 + e4] = acc0;
        red4[(g * 4 + 1) * 64 + e4] = acc1;
        red4[(g * 4 + 2) * 64 + e4] = acc2;
        red4[(g * 4 + 3) * 64 + e4] = acc3;
        __syncthreads();

        const int row = t >> 6, ee = t & 63;     // 4 rows x 64 e4 = 256 threads
        float4 s0 = red4[(0 * 4 + row) * 64 + ee];
        float4 s1 = red4[(1 * 4 + row) * 64 + ee];
        float4 s2 = red4[(2 * 4 + row) * 64 + ee];
        float4 s3 = red4[(3 * 4 + row) * 64 + ee];
        float4 s;
        s.x = s0.x + s1.x + s2.x + s3.x;
        s.y = s0.y + s1.y + s2.y + s3.y;
        s.z = s0.z + s1.z + s2.z + s3.z;
        s.w = s0.w + s1.w + s2.w + s3.w;

        float* P = ws_w + WS_P;
        size_t base = ((size_t)(r0 + row) * 256 + ee * 4) * 4 + c;
        P[base + 0 * 4] = s.x;
        P[base + 1 * 4] = s.y;
        P[base + 2 * 4] = s.z;
        P[base + 3 * 4] = s.w;
    } else {
        // ---- E branch: block = (b, h, sq-tile of 4) ----
        __shared__ float q_s[4 * 32];
        __shared__ float es[4 * CK];      // exp(scores) 4 sq x 600 ck
        int idx = blockIdx.x - 200;       // [0,400)
        int b   = idx / 200;
        int rem = idx - b * 200;
        int h   = rem / 25;
        int sqt = rem - h * 25;
        int sq0 = sqt * 4;

        if (t < 128)
            q_s[t] = query[(size_t)(b * L + sq0 + (t >> 5)) * EMBD + h * HS + (t & 31)];
        __syncthreads();

        const float scale = 0.17677669529663687f;  // 1/sqrt(32)
        const float4* kt4 = reinterpret_cast<const float4*>(ws_r + WS_KTR)
                          + (size_t)(b * N_HEADS + h) * 8 * CK;

#pragma unroll
        for (int i = 0; i < 3; ++i) {
            int ck = t + i * 256;
            if (ck < CK) {
                float acc0 = 0.f, acc1 = 0.f, acc2 = 0.f, acc3 = 0.f;
#pragma unroll
                for (int d4 = 0; d4 < 8; ++d4) {
                    float4 kv = kt4[(size_t)d4 * CK + ck];   // 16B/lane coalesced
                    const float* q0 = &q_s[0 * 32 + d4 * 4];
                    const float* q1 = &q_s[1 * 32 + d4 * 4];
                    const float* q2 = &q_s[2 * 32 + d4 * 4];
                    const float* q3 = &q_s[3 * 32 + d4 * 4];
                    acc0 += q0[0] * kv.x + q0[1] * kv.y + q0[2] * kv.z + q0[3] * kv.w;
                    acc1 += q1[0] * kv.x + q1[1] * kv.y + q1[2] * kv.z + q1[3] * kv.w;
                    acc2 += q2[0] * kv.x + q2[1] * kv.y + q2[2] * kv.z + q2[3] * kv.w;
                    acc3 += q3[0] * kv.x + q3[1] * kv.y + q3[2] * kv.z + q3[3] * kv.w;
                }
                es[0 * CK + ck] = __expf(acc0 * scale);
                es[1 * CK + ck] = __expf(acc1 * scale);
                es[2 * CK + ck] = __expf(acc2 * scale);
                es[3 * CK + ck] = __expf(acc3 * scale);
            }
        }
        __syncthreads();

        // camera fold -> E
        float* E = ws_w + WS_E;
        for (int p = t; p < 4 * L; p += 256) {
            int sj = p / 100, sk = p - sj * 100;
            float e = 0.f;
#pragma unroll
            for (int cam = 0; cam < N_CAM; ++cam)
                e += es[sj * CK + cam * L + sk];
            E[((size_t)(b * L + sq0 + sj) * N_HEADS + h) * L + sk] = e;
        }
    }
}

// ---------------------------------------------------------------------------
// L3 (100 blocks): block = (b, sq-pair). P[b] slab amortized over 2 queries
// (82 -> 41 MB L2 traffic).
// out[b,sq,e] = (sum_sk E*(p.x+p.y+p.z+p.w) + sumE*bias_e) * 0.25/sumE
// ---------------------------------------------------------------------------
__global__ __launch_bounds__(256) void out_kernel(const float* __restrict__ ws,
                                                  const float* __restrict__ b_v,
                                                  float* __restrict__ out) {
    __shared__ float E_s[2 * N_HEADS * L];    // 1600 floats, 2 queries
    const int t   = threadIdx.x;
    const int b   = blockIdx.x / 50;
    const int sq0 = (blockIdx.x - b * 50) * 2;

    const float* E = ws + WS_E + (size_t)(b * L + sq0) * N_HEADS * L;
    for (int i = t; i < 2 * N_HEADS * L; i += 256) E_s[i] = E[i];
    __syncthreads();

    const int h = t >> 5;
    float sumE0 = 0.f, sumE1 = 0.f;
#pragma unroll 4
    for (int sk = 0; sk < L; ++sk) {
        sumE0 += E_s[h * L + sk];                 // broadcast reads (free)
        sumE1 += E_s[N_HEADS * L + h * L + sk];
    }

    float bias = b_v[t] + b_v[256 + t] + b_v[512 + t] + b_v[768 + t];

    const float4* p4 = (const float4*)(ws + WS_P) + (size_t)b * L * 256 + t;
    float acc0 = 0.f, acc1 = 0.f;
#pragma unroll 16
    for (int sk = 0; sk < L; ++sk) {
        float4 p = p4[(size_t)sk * 256];  // 16B coalesced, folds 4 K-chunks
        float s = p.x + p.y + p.z + p.w;
        acc0 += E_s[h * L + sk] * s;
        acc1 += E_s[N_HEADS * L + h * L + sk] * s;
    }

    out[(size_t)(b * L + sq0 + 0) * EMBD + t] = (acc0 + sumE0 * bias) * (0.25f / sumE0);
    out[(size_t)(b * L + sq0 + 1) * EMBD + t] = (acc1 + sumE1 * bias) * (0.25f / sumE1);
}

// ---------------------------------------------------------------------------
extern "C" void kernel_launch(void* const* d_in, const int* in_sizes, int n_in,
                              void* d_out, int out_size, void* d_ws, size_t ws_size,
                              hipStream_t stream) {
    const float* feat  = (const float*)d_in[0];  // (2,1,6,256,10,10)
    const float* query = (const float*)d_in[1];  // (2,100,256)
    const float4* Wv   = (const float4*)d_in[2]; // (1536,1024)
    const float* bv    = (const float*)d_in[3];  // (1024,)
    float* outp = (float*)d_out;                 // (2,100,256)
    float* ws   = (float*)d_ws;

    // L1: float4-packed ktr transpose + W fold (independent, one launch)
    prep_kernel<<<480, 256, 0, stream>>>(feat, Wv, ws);
    // L2: split-K GEMM (200 blk, 4-row float4) + float4 E-compute (400 blk)
    mid_kernel<<<600, 256, 0, stream>>>(feat, query, ws, ws);
    // L3: E-weighted reduce + bias + normalize, 2 sq per block
    out_kernel<<<100, 256, 0, stream>>>(ws, bv, outp);
}